// Round 5
// baseline (288.054 us; speedup 1.0000x reference)
//
#include <hip/hip_runtime.h>
#include <math.h>

#define N_NODES 200000
#define K_DEG 16
#define G_GRAPHS 4000
#define F_IN 25
#define EPSV 1e-5f

__device__ inline unsigned short f2bf(float f) {
    unsigned int u = __float_as_uint(f);
    u += 0x7fff + ((u >> 16) & 1);            // RNE
    return (unsigned short)(u >> 16);
}
__device__ inline float bf2f(unsigned short h) {
    return __uint_as_float(((unsigned int)h) << 16);
}

// ---------------------------------------------------------------------------
// pre1: per 256-node tile: c1 = Ws1@x (bf16 pairs, 16-uint rows) and d1 = P1@x.
// Self-folds P1 = A1@Wd1 (deg==16 -> scalers identity, dst-side linear).
// ---------------------------------------------------------------------------
__global__ void __launch_bounds__(256) pre1(const float* __restrict__ x,
                                            const float* __restrict__ w1_pre,
                                            const float* __restrict__ w1_post,
                                            const float* __restrict__ w1_lin,
                                            unsigned int* __restrict__ c1b_dw,
                                            float* __restrict__ d1) {
    __shared__ float xs[256 * 25];
    __shared__ float wls[25 * 25];
    __shared__ float pls[16 * 25];
    __shared__ float u1[16 * 25];
    __shared__ float a1s[16 * 25];
    __shared__ float wl[256];
    __shared__ unsigned int otile[256 * 17];
    int tid = threadIdx.x;
    int base = blockIdx.x * 256;
    for (int i = tid; i < 6400; i += 256) {
        int g = base * 25 + i;
        xs[i] = (g < N_NODES * F_IN) ? x[g] : 0.f;
    }
    for (int i = tid; i < 625; i += 256) {
        int f = i / 25, k = i % 25;
        wls[i] = w1_pre[f * 50 + 25 + k];          // src half
    }
    wl[tid] = w1_lin[tid];
    for (int i = tid; i < 400; i += 256) {         // U1 row-sums of w1_post
        int h = i / 25, f = i % 25;
        const float* wp = w1_post + h * 300 + f;
        u1[i] = wp[0] + wp[25] + wp[50] + wp[100] + wp[125] + wp[150] +
                wp[200] + wp[225] + wp[250];
    }
    __syncthreads();
    for (int i = tid; i < 400; i += 256) {         // A1 = w1_lin @ U1
        int o = i / 25, f = i % 25;
        float s = 0.f;
#pragma unroll
        for (int h = 0; h < 16; ++h) s += wl[o * 16 + h] * u1[h * 25 + f];
        a1s[i] = s;
    }
    __syncthreads();
    for (int i = tid; i < 400; i += 256) {         // P1 = A1 @ Wd1
        int o = i / 25, k = i % 25;
        float s = 0.f;
#pragma unroll
        for (int f = 0; f < 25; ++f) s += a1s[o * 25 + f] * w1_pre[f * 50 + k];
        pls[i] = s;
    }
    __syncthreads();

    float xr[25];
#pragma unroll
    for (int k = 0; k < 25; ++k) xr[k] = xs[tid * 25 + k];

    unsigned int pk[16];
#pragma unroll
    for (int j = 0; j < 16; ++j) pk[j] = 0;
#pragma unroll
    for (int f = 0; f < 25; ++f) {
        float s = 0.f;
#pragma unroll
        for (int k = 0; k < 25; ++k) s += wls[f * 25 + k] * xr[k];
        unsigned int b = f2bf(s);
        pk[f >> 1] |= (f & 1) ? (b << 16) : b;
    }
#pragma unroll
    for (int j = 0; j < 16; ++j) otile[tid * 17 + j] = pk[j];
    __syncthreads();
    for (int i = tid; i < 4096; i += 256) {
        int g = base * 16 + i;
        if (g < N_NODES * 16) c1b_dw[g] = otile[(i >> 4) * 17 + (i & 15)];
    }
    __syncthreads();

    float* ftile = (float*)otile;
#pragma unroll
    for (int o = 0; o < 16; ++o) {
        float s = 0.f;
#pragma unroll
        for (int k = 0; k < 25; ++k) s += pls[o * 25 + k] * xr[k];
        ftile[tid * 17 + o] = s;
    }
    __syncthreads();
    for (int i = tid; i < 4096; i += 256) {
        int g = base * 16 + i;
        if (g < N_NODES * 16) d1[g] = ftile[(i >> 4) * 17 + (i & 15)];
    }
}

// ---------------------------------------------------------------------------
// agg1: 32 nodes/block, 8 lanes/node, uint2 gathers (4 feats/lane, 64 B/row).
// Self-folds C1 (padded 4x28 layout), bvp1, P2, Ws2.  h1 stays in LDS;
// epilogue emits c2b (bf16) + d2.
// ---------------------------------------------------------------------------
__global__ void __launch_bounds__(256) agg1(const uint2* __restrict__ c1u2,
                                            const int* __restrict__ src,
                                            const float* __restrict__ d1,
                                            const float* __restrict__ w1_post,
                                            const float* __restrict__ w1_lin,
                                            const float* __restrict__ b1_post,
                                            const float* __restrict__ b1_lin,
                                            const float* __restrict__ b1_pre,
                                            const float* __restrict__ w2_pre,
                                            const float* __restrict__ w2_post,
                                            const float* __restrict__ w2_lin,
                                            unsigned short* __restrict__ c2b,
                                            float* __restrict__ d2) {
    __shared__ float cs[16 * 116];     // stat stride 28 (25 + 3 zero pads), row stride 116
    __shared__ float aggs[32 * 116];
    __shared__ float h1s[32 * 17];
    __shared__ float ws2[16 * 17];
    __shared__ float p2s[8 * 17];
    __shared__ float bvs[16];
    __shared__ float wl1[256];
    __shared__ float wl2[64];
    __shared__ int idxs[512];
    int tid = threadIdx.x;
    float* T1  = aggs;            // 1600  (scratch, overwritten by gather)
    float* T2  = aggs + 1600;     // 512
    float* A1f = aggs + 2112;     // 400
    float* A2f = aggs + 2512;     // 128

    // phase 1: stage row-sum tables + small weights
    for (int i = tid; i < 1600; i += 256) {
        int h = i / 100, j = i % 100;
        const float* wp = w1_post + h * 300 + j;
        T1[i] = wp[0] + wp[100] + wp[200];
    }
    for (int i = tid; i < 512; i += 256) {
        int h = i >> 6, j = i & 63;
        const float* wp = w2_post + h * 192 + j;
        T2[i] = wp[0] + wp[64] + wp[128];
    }
    wl1[tid] = w1_lin[tid];
    if (tid < 64) wl2[tid] = w2_lin[tid];
    { int f = tid >> 4, k = tid & 15; ws2[f * 17 + k] = w2_pre[f * 32 + 16 + k]; }
    __syncthreads();
    // phase 2a: cs = folded post matrix, padded layout
    for (int i = tid; i < 1792; i += 256) {
        int o = i / 112, c = i % 112;
        int st = c / 28, f = c % 28;
        float s = 0.f;
        if (f < 25) {
            const float* tr = T1 + st * 25 + f;
#pragma unroll
            for (int h = 0; h < 16; ++h) s += wl1[o * 16 + h] * tr[h * 100];
        }
        cs[o * 116 + c] = s;
    }
    __syncthreads();
    // phase 2b: A1, A2
    for (int i = tid; i < 400; i += 256) {
        int o = i / 25, f = i % 25;
        A1f[i] = cs[o * 116 + f] + cs[o * 116 + 28 + f] + cs[o * 116 + 56 + f];
    }
    if (tid < 128) {
        int o = tid >> 4, f = tid & 15;
        float s = 0.f;
#pragma unroll
        for (int h = 0; h < 8; ++h)
            s += wl2[o * 8 + h] * (T2[h * 64 + f] + T2[h * 64 + 16 + f] + T2[h * 64 + 32 + f]);
        A2f[tid] = s;
    }
    __syncthreads();
    // phase 3: P2, bvp1, edge indices
    if (tid < 128) {
        int o = tid >> 4, k = tid & 15;
        float s = 0.f;
#pragma unroll
        for (int f = 0; f < 16; ++f) s += A2f[o * 16 + f] * w2_pre[f * 32 + k];
        p2s[o * 17 + k] = s;
    }
    if (tid < 16) {
        float s = b1_lin[tid];
#pragma unroll
        for (int h = 0; h < 16; ++h) s += wl1[tid * 16 + h] * b1_post[h];
#pragma unroll
        for (int f = 0; f < 25; ++f) s += A1f[tid * 25 + f] * b1_pre[f];
        bvs[tid] = s;
    }
    idxs[tid] = src[blockIdx.x * 512 + tid];
    idxs[256 + tid] = src[blockIdx.x * 512 + 256 + tid];
    __syncthreads();

    // gather + aggregate (overwrites aggs scratch)
    int g = tid >> 3, L = tid & 7;      // node-in-block, lane covers feats 4L..4L+3
    float s0 = 0.f, s1 = 0.f, s2 = 0.f, s3 = 0.f;
    float q0 = 0.f, q1 = 0.f, q2 = 0.f, q3 = 0.f;
    float n0 = 1e30f, n1 = 1e30f, n2 = 1e30f, n3 = 1e30f;
    float x0 = -1e30f, x1 = -1e30f, x2 = -1e30f, x3 = -1e30f;
#pragma unroll
    for (int b = 0; b < 2; ++b) {
        int id[8];
#pragma unroll
        for (int e = 0; e < 8; ++e) id[e] = idxs[g * 16 + b * 8 + e];
        uint2 v[8];
#pragma unroll
        for (int e = 0; e < 8; ++e) v[e] = c1u2[id[e] * 8 + L];
#pragma unroll
        for (int e = 0; e < 8; ++e) {
            float a = bf2f((unsigned short)(v[e].x & 0xffff));
            float bb = bf2f((unsigned short)(v[e].x >> 16));
            float c = bf2f((unsigned short)(v[e].y & 0xffff));
            float dd = bf2f((unsigned short)(v[e].y >> 16));
            s0 += a;  q0 += a * a;   n0 = fminf(n0, a);  x0 = fmaxf(x0, a);
            s1 += bb; q1 += bb * bb; n1 = fminf(n1, bb); x1 = fmaxf(x1, bb);
            s2 += c;  q2 += c * c;   n2 = fminf(n2, c);  x2 = fmaxf(x2, c);
            s3 += dd; q3 += dd * dd; n3 = fminf(n3, dd); x3 = fmaxf(x3, dd);
        }
    }
    float me0 = s0 * (1.f / 16.f), me1 = s1 * (1.f / 16.f);
    float me2 = s2 * (1.f / 16.f), me3 = s3 * (1.f / 16.f);
    float sd0 = sqrtf(fmaxf(q0 * (1.f / 16.f) - me0 * me0, 0.f) + EPSV);
    float sd1 = sqrtf(fmaxf(q1 * (1.f / 16.f) - me1 * me1, 0.f) + EPSV);
    float sd2 = sqrtf(fmaxf(q2 * (1.f / 16.f) - me2 * me2, 0.f) + EPSV);
    float sd3 = sqrtf(fmaxf(q3 * (1.f / 16.f) - me3 * me3, 0.f) + EPSV);
    {
        float* r = aggs + g * 116 + 4 * L;
        if (L < 6) {
            *(float4*)(r)      = make_float4(me0, me1, me2, me3);
            *(float4*)(r + 28) = make_float4(n0, n1, n2, n3);
            *(float4*)(r + 56) = make_float4(x0, x1, x2, x3);
            *(float4*)(r + 84) = make_float4(sd0, sd1, sd2, sd3);
        } else if (L == 6) {               // feats 24 valid, 25..27 are pads
            *(float4*)(r)      = make_float4(me0, 0.f, 0.f, 0.f);
            *(float4*)(r + 28) = make_float4(n0, 0.f, 0.f, 0.f);
            *(float4*)(r + 56) = make_float4(x0, 0.f, 0.f, 0.f);
            *(float4*)(r + 84) = make_float4(sd0, 0.f, 0.f, 0.f);
        }                                   // L == 7: feats 28..31 don't exist
    }
    __syncthreads();

    // h1 = relu(cs @ agg + d1 + bvp1)
#pragma unroll
    for (int r2 = 0; r2 < 2; ++r2) {
        int t2 = tid + 256 * r2;
        int nl = t2 >> 4, o = t2 & 15;
        int nn = blockIdx.x * 32 + nl;
        float s = bvs[o] + d1[nn * 16 + o];
        const float4* c4 = (const float4*)(cs + o * 116);
        const float4* a4 = (const float4*)(aggs + nl * 116);
#pragma unroll
        for (int j = 0; j < 28; ++j) {
            float4 cv = c4[j], av = a4[j];
            s += cv.x * av.x + cv.y * av.y + cv.z * av.z + cv.w * av.w;
        }
        h1s[nl * 17 + o] = fmaxf(s, 0.f);
    }
    __syncthreads();

    // epilogue: c2 = Ws2@h1 (bf16), d2 = P2@h1
#pragma unroll
    for (int r2 = 0; r2 < 2; ++r2) {
        int t2 = tid + 256 * r2;
        int nl = t2 >> 4, f = t2 & 15;
        int nn = blockIdx.x * 32 + nl;
        const float* hr = h1s + nl * 17;
        float s = 0.f;
#pragma unroll
        for (int k = 0; k < 16; ++k) s += ws2[f * 17 + k] * hr[k];
        c2b[nn * 16 + f] = f2bf(s);
    }
    {
        int nl = tid >> 3, o = tid & 7;
        int nn = blockIdx.x * 32 + nl;
        const float* hr = h1s + nl * 17;
        float s = 0.f;
#pragma unroll
        for (int k = 0; k < 16; ++k) s += p2s[o * 17 + k] * hr[k];
        d2[nn * 8 + o] = s;
    }
}

// ---------------------------------------------------------------------------
// agg2: 64 nodes/block, 4 lanes/node, uint2 gathers (4 feats/lane, 32 B/row).
// Self-folds C2 + bvp2.  h2 = relu(M2@agg + d2 + bvp2).
// ---------------------------------------------------------------------------
__global__ void __launch_bounds__(256) agg2(const uint2* __restrict__ c2u2,
                                            const int* __restrict__ src,
                                            const float* __restrict__ d2,
                                            const float* __restrict__ w2_post,
                                            const float* __restrict__ w2_lin,
                                            const float* __restrict__ b2_post,
                                            const float* __restrict__ b2_lin,
                                            const float* __restrict__ b2_pre,
                                            float* __restrict__ h2) {
    __shared__ float cs2[8 * 68];
    __shared__ float aggs2[64 * 68];
    __shared__ float wl2[64];
    __shared__ float bvs2[8];
    __shared__ int idxs[1024];
    int tid = threadIdx.x;
    float* T2  = aggs2;          // 512 scratch
    float* A2f = aggs2 + 512;    // 128

    for (int i = tid; i < 512; i += 256) {
        int h = i >> 6, j = i & 63;
        const float* wp = w2_post + h * 192 + j;
        T2[i] = wp[0] + wp[64] + wp[128];
    }
    if (tid < 64) wl2[tid] = w2_lin[tid];
    __syncthreads();
    for (int i = tid; i < 544; i += 256) {
        int o = i / 68, c = i % 68;
        float s = 0.f;
        if (c < 64) {
            const float* tr = T2 + c;
#pragma unroll
            for (int h = 0; h < 8; ++h) s += wl2[o * 8 + h] * tr[h * 64];
        }
        cs2[i] = s;
    }
    __syncthreads();
    if (tid < 128) {
        int o = tid >> 4, f = tid & 15;
        A2f[tid] = cs2[o * 68 + f] + cs2[o * 68 + 16 + f] + cs2[o * 68 + 32 + f];
    }
    __syncthreads();
    if (tid < 8) {
        float s = b2_lin[tid];
#pragma unroll
        for (int h = 0; h < 8; ++h) s += wl2[tid * 8 + h] * b2_post[h];
#pragma unroll
        for (int f = 0; f < 16; ++f) s += A2f[tid * 16 + f] * b2_pre[f];
        bvs2[tid] = s;
    }
#pragma unroll
    for (int r2 = 0; r2 < 4; ++r2)
        idxs[tid + 256 * r2] = src[blockIdx.x * 1024 + 256 * r2 + tid];
    __syncthreads();

    int g = tid >> 2, L = tid & 3;       // node-in-block, feats 4L..4L+3
    float s0 = 0.f, s1 = 0.f, s2 = 0.f, s3 = 0.f;
    float q0 = 0.f, q1 = 0.f, q2 = 0.f, q3 = 0.f;
    float n0 = 1e30f, n1 = 1e30f, n2 = 1e30f, n3 = 1e30f;
    float x0 = -1e30f, x1 = -1e30f, x2 = -1e30f, x3 = -1e30f;
#pragma unroll
    for (int b = 0; b < 2; ++b) {
        int id[8];
#pragma unroll
        for (int e = 0; e < 8; ++e) id[e] = idxs[g * 16 + b * 8 + e];
        uint2 v[8];
#pragma unroll
        for (int e = 0; e < 8; ++e) v[e] = c2u2[id[e] * 4 + L];
#pragma unroll
        for (int e = 0; e < 8; ++e) {
            float a = bf2f((unsigned short)(v[e].x & 0xffff));
            float bb = bf2f((unsigned short)(v[e].x >> 16));
            float c = bf2f((unsigned short)(v[e].y & 0xffff));
            float dd = bf2f((unsigned short)(v[e].y >> 16));
            s0 += a;  q0 += a * a;   n0 = fminf(n0, a);  x0 = fmaxf(x0, a);
            s1 += bb; q1 += bb * bb; n1 = fminf(n1, bb); x1 = fmaxf(x1, bb);
            s2 += c;  q2 += c * c;   n2 = fminf(n2, c);  x2 = fmaxf(x2, c);
            s3 += dd; q3 += dd * dd; n3 = fminf(n3, dd); x3 = fmaxf(x3, dd);
        }
    }
    float me0 = s0 * (1.f / 16.f), me1 = s1 * (1.f / 16.f);
    float me2 = s2 * (1.f / 16.f), me3 = s3 * (1.f / 16.f);
    float sd0 = sqrtf(fmaxf(q0 * (1.f / 16.f) - me0 * me0, 0.f) + EPSV);
    float sd1 = sqrtf(fmaxf(q1 * (1.f / 16.f) - me1 * me1, 0.f) + EPSV);
    float sd2 = sqrtf(fmaxf(q2 * (1.f / 16.f) - me2 * me2, 0.f) + EPSV);
    float sd3 = sqrtf(fmaxf(q3 * (1.f / 16.f) - me3 * me3, 0.f) + EPSV);
    {
        float* r = aggs2 + g * 68 + 4 * L;
        *(float4*)(r)      = make_float4(me0, me1, me2, me3);
        *(float4*)(r + 16) = make_float4(n0, n1, n2, n3);
        *(float4*)(r + 32) = make_float4(x0, x1, x2, x3);
        *(float4*)(r + 48) = make_float4(sd0, sd1, sd2, sd3);
        if (L == 0) *(float4*)(aggs2 + g * 68 + 64) = make_float4(0.f, 0.f, 0.f, 0.f);
    }
    __syncthreads();

#pragma unroll
    for (int r2 = 0; r2 < 2; ++r2) {
        int t2 = tid + 256 * r2;
        int nl = t2 >> 3, o = t2 & 7;
        int nn = blockIdx.x * 64 + nl;
        float s = bvs2[o] + d2[nn * 8 + o];
        const float4* c4 = (const float4*)(cs2 + o * 68);
        const float4* a4 = (const float4*)(aggs2 + nl * 68);
#pragma unroll
        for (int j = 0; j < 17; ++j) {
            float4 cv = c4[j], av = a4[j];
            s += cv.x * av.x + cv.y * av.y + cv.z * av.z + cv.w * av.w;
        }
        h2[nn * 8 + o] = fmaxf(s, 0.f);
    }
}

// ---------------------------------------------------------------------------
// pool (50 contiguous nodes / graph) + fc + log_softmax.  1 wave per graph.
// ---------------------------------------------------------------------------
__global__ void pool_fc(const float* __restrict__ h2, const float* __restrict__ fc_w,
                        const float* __restrict__ fc_b, float* __restrict__ out) {
    int wave = threadIdx.x >> 6;
    int lane = threadIdx.x & 63;
    int g = blockIdx.x * 4 + wave;
    float s0 = 0.f, s1 = 0.f;
    if (lane < 50) {
        const float* hr = h2 + (g * 50 + lane) * 8;
        float v[8];
#pragma unroll
        for (int o = 0; o < 8; ++o) v[o] = hr[o];
#pragma unroll
        for (int o = 0; o < 8; ++o) { s0 += fc_w[o] * v[o]; s1 += fc_w[8 + o] * v[o]; }
    }
#pragma unroll
    for (int off = 32; off > 0; off >>= 1) {
        s0 += __shfl_down(s0, off);
        s1 += __shfl_down(s1, off);
    }
    if (lane == 0) {
        float l0 = s0 + fc_b[0], l1 = s1 + fc_b[1];
        float m = fmaxf(l0, l1);
        float lse = m + logf(expf(l0 - m) + expf(l1 - m));
        out[g * 2]     = l0 - lse;
        out[g * 2 + 1] = l1 - lse;
    }
}

extern "C" void kernel_launch(void* const* d_in, const int* in_sizes, int n_in,
                              void* d_out, int out_size, void* d_ws, size_t ws_size,
                              hipStream_t stream) {
    const float* x       = (const float*)d_in[0];
    const int*   eidx    = (const int*)d_in[1];   // [2][E]; row 0 = src
    const float* w1_pre  = (const float*)d_in[3];
    const float* b1_pre  = (const float*)d_in[4];
    const float* w1_post = (const float*)d_in[5];
    const float* b1_post = (const float*)d_in[6];
    const float* w1_lin  = (const float*)d_in[7];
    const float* b1_lin  = (const float*)d_in[8];
    const float* w2_pre  = (const float*)d_in[9];
    const float* b2_pre  = (const float*)d_in[10];
    const float* w2_post = (const float*)d_in[11];
    const float* b2_post = (const float*)d_in[12];
    const float* w2_lin  = (const float*)d_in[13];
    const float* b2_lin  = (const float*)d_in[14];
    const float* fc_w    = (const float*)d_in[15];
    const float* fc_b    = (const float*)d_in[16];
    float* out = (float*)d_out;
    const int* src = eidx;

    char* ws = (char*)d_ws;
    unsigned int*   c1u = (unsigned int*)ws;                  // N*16*4  = 12.8 MB
    unsigned short* c2b = (unsigned short*)(ws + 12800000);   // N*16*2  =  6.4 MB
    float* d1  = (float*)(ws + 19200000);                     // N*16*4  = 12.8 MB
    float* d2  = (float*)(ws + 32000000);                     // N*8*4   =  6.4 MB
    float* h2  = (float*)(ws + 38400000);                     // N*8*4   =  6.4 MB

    pre1<<<(N_NODES + 255) / 256, 256, 0, stream>>>(x, w1_pre, w1_post, w1_lin, c1u, d1);
    agg1<<<N_NODES / 32, 256, 0, stream>>>((const uint2*)c1u, src, d1,
                                           w1_post, w1_lin, b1_post, b1_lin, b1_pre,
                                           w2_pre, w2_post, w2_lin, c2b, d2);
    agg2<<<N_NODES / 64, 256, 0, stream>>>((const uint2*)c2b, src, d2,
                                           w2_post, w2_lin, b2_post, b2_lin, b2_pre, h2);
    pool_fc<<<G_GRAPHS / 4, 256, 0, stream>>>(h2, fc_w, fc_b, out);
}

// Round 7
// 235.171 us; speedup vs baseline: 1.2249x; 1.2249x over previous
//
#include <hip/hip_runtime.h>
#include <math.h>

#define N_NODES 200000
#define K_DEG 16
#define G_GRAPHS 4000
#define F_IN 25
#define EPSV 1e-5f

__device__ inline unsigned short f2bf(float f) {
    unsigned int u = __float_as_uint(f);
    u += 0x7fff + ((u >> 16) & 1);            // RNE
    return (unsigned short)(u >> 16);
}
__device__ inline float bf2f(unsigned short h) {
    return __uint_as_float(((unsigned int)h) << 16);
}

// ---------------------------------------------------------------------------
// prep: fold weights (deg==16 -> scalers identity, dst-side linear & foldable).
// Two independent blocks:
//   block 0 (layer 1): C1ext 16x108 padded [mean25|p|min25|p|max25|p|std25|p|pad4],
//                      P1 = A1@Wd1 (16x25), bvp1[16]
//   block 1 (layer 2): C2p 8x68 padded, P2 = A2@Wd2 (8x16), bvp2[8]
// ---------------------------------------------------------------------------
__global__ void prep(const float* __restrict__ w1_pre, const float* __restrict__ b1_pre,
                     const float* __restrict__ w1_post, const float* __restrict__ b1_post,
                     const float* __restrict__ w1_lin, const float* __restrict__ b1_lin,
                     const float* __restrict__ w2_pre, const float* __restrict__ b2_pre,
                     const float* __restrict__ w2_post, const float* __restrict__ b2_post,
                     const float* __restrict__ w2_lin, const float* __restrict__ b2_lin,
                     float* __restrict__ C1ext, float* __restrict__ bvp1, float* __restrict__ P1,
                     float* __restrict__ C2p, float* __restrict__ bvp2, float* __restrict__ P2) {
    int tid = threadIdx.x;
    if (blockIdx.x == 0) {
        __shared__ float wp[4800];
        __shared__ float wl[256];
        __shared__ float mm[1600];
        __shared__ float aa[400];
        for (int i = tid; i < 4800; i += 256) wp[i] = w1_post[i];
        wl[tid] = w1_lin[tid];
        __syncthreads();
        for (int i = tid; i < 1600; i += 256) {
            int o = i / 100, j = i % 100;
            float s = 0.f;
#pragma unroll
            for (int h = 0; h < 16; ++h)
                s += wl[o * 16 + h] * (wp[h * 300 + j] + wp[h * 300 + 100 + j] + wp[h * 300 + 200 + j]);
            mm[i] = s;
        }
        __syncthreads();
        for (int i = tid; i < 400; i += 256) {
            int o = i / 25, f = i % 25;
            aa[i] = mm[o * 100 + f] + mm[o * 100 + 25 + f] + mm[o * 100 + 50 + f];
        }
        __syncthreads();
        for (int i = tid; i < 1728; i += 256) {
            int o = i / 108, c = i % 108;
            int st = c / 26, f = c % 26;
            C1ext[i] = (c < 104 && f < 25) ? mm[o * 100 + st * 25 + f] : 0.f;
        }
        for (int i = tid; i < 400; i += 256) {       // P1 = A1 @ Wd1
            int o = i / 25, k = i % 25;
            float s = 0.f;
#pragma unroll
            for (int f = 0; f < 25; ++f) s += aa[o * 25 + f] * w1_pre[f * 50 + k];
            P1[i] = s;
        }
        if (tid < 16) {
            float s = b1_lin[tid];
#pragma unroll
            for (int h = 0; h < 16; ++h) s += wl[tid * 16 + h] * b1_post[h];
#pragma unroll
            for (int f = 0; f < 25; ++f) s += aa[tid * 25 + f] * b1_pre[f];
            bvp1[tid] = s;
        }
    } else {
        __shared__ float wp2[1536];
        __shared__ float wl2[64];
        __shared__ float mm2[512];
        __shared__ float aa2[128];
        for (int i = tid; i < 1536; i += 256) wp2[i] = w2_post[i];
        if (tid < 64) wl2[tid] = w2_lin[tid];
        __syncthreads();
        for (int i = tid; i < 512; i += 256) {
            int o = i / 64, j = i % 64;
            float s = 0.f;
#pragma unroll
            for (int h = 0; h < 8; ++h)
                s += wl2[o * 8 + h] * (wp2[h * 192 + j] + wp2[h * 192 + 64 + j] + wp2[h * 192 + 128 + j]);
            mm2[i] = s;
        }
        __syncthreads();
        if (tid < 128) {
            int o = tid / 16, f = tid % 16;
            aa2[tid] = mm2[o * 64 + f] + mm2[o * 64 + 16 + f] + mm2[o * 64 + 32 + f];
        }
        __syncthreads();
        for (int i = tid; i < 544; i += 256) {
            int o = i / 68, c = i % 68;
            C2p[i] = (c < 64) ? mm2[o * 64 + c] : 0.f;
        }
        if (tid < 128) {
            int o = tid / 16, k = tid % 16;
            float s = 0.f;
#pragma unroll
            for (int f = 0; f < 16; ++f) s += aa2[o * 16 + f] * w2_pre[f * 32 + k];
            P2[tid] = s;
        }
        if (tid < 8) {
            float s = b2_lin[tid];
#pragma unroll
            for (int h = 0; h < 8; ++h) s += wl2[tid * 8 + h] * b2_post[h];
#pragma unroll
            for (int f = 0; f < 16; ++f) s += aa2[tid * 16 + f] * b2_pre[f];
            bvp2[tid] = s;
        }
    }
}

// ---------------------------------------------------------------------------
// pre1: per 256-node tile: c1 = Ws1@x (bf16 pairs, 16-uint rows) and d1 = P1@x.
// ---------------------------------------------------------------------------
__global__ void __launch_bounds__(256) pre1(const float* __restrict__ x,
                                            const float* __restrict__ w1_pre,
                                            const float* __restrict__ P1,
                                            unsigned int* __restrict__ c1b_dw,
                                            float* __restrict__ d1) {
    __shared__ float xs[256 * 25];
    __shared__ float wls[25 * 25];
    __shared__ float pls[16 * 25];
    __shared__ unsigned int otile[256 * 17];
    int tid = threadIdx.x;
    int base = blockIdx.x * 256;
    for (int i = tid; i < 6400; i += 256) {
        int g = base * 25 + i;
        xs[i] = (g < N_NODES * F_IN) ? x[g] : 0.f;
    }
    for (int i = tid; i < 625; i += 256) {
        int f = i / 25, k = i % 25;
        wls[i] = w1_pre[f * 50 + 25 + k];
    }
    for (int i = tid; i < 400; i += 256) pls[i] = P1[i];
    __syncthreads();

    float xr[25];
#pragma unroll
    for (int k = 0; k < 25; ++k) xr[k] = xs[tid * 25 + k];

    unsigned int pk[16];
#pragma unroll
    for (int j = 0; j < 16; ++j) pk[j] = 0;
#pragma unroll
    for (int f = 0; f < 25; ++f) {
        float s = 0.f;
#pragma unroll
        for (int k = 0; k < 25; ++k) s += wls[f * 25 + k] * xr[k];
        unsigned int b = f2bf(s);
        pk[f >> 1] |= (f & 1) ? (b << 16) : b;
    }
#pragma unroll
    for (int j = 0; j < 16; ++j) otile[tid * 17 + j] = pk[j];
    __syncthreads();
    for (int i = tid; i < 4096; i += 256) {
        int g = base * 16 + i;
        if (g < N_NODES * 16) c1b_dw[g] = otile[(i >> 4) * 17 + (i & 15)];
    }
    __syncthreads();

    float* ftile = (float*)otile;
#pragma unroll
    for (int o = 0; o < 16; ++o) {
        float s = 0.f;
#pragma unroll
        for (int k = 0; k < 25; ++k) s += pls[o * 25 + k] * xr[k];
        ftile[tid * 17 + o] = s;
    }
    __syncthreads();
    for (int i = tid; i < 4096; i += 256) {
        int g = base * 16 + i;
        if (g < N_NODES * 16) d1[g] = ftile[(i >> 4) * 17 + (i & 15)];
    }
}

// ---------------------------------------------------------------------------
// agg1: 16 lanes/node, 16 nodes/block.  uint gathers (2 feats/lane), coalesced
// LDS-staged edge indices.  h1 in LDS, epilogue emits c2b (bf16) + d2.
// (R4-proven configuration: ~250k LDS conflicts, ~72% occupancy, 2.9 TB/s.)
// ---------------------------------------------------------------------------
__global__ void __launch_bounds__(256) agg1(const unsigned int* __restrict__ c1u,
                                            const int* __restrict__ src,
                                            const float* __restrict__ d1,
                                            const float* __restrict__ C1ext,
                                            const float* __restrict__ bvp1,
                                            const float* __restrict__ w2_pre,
                                            const float* __restrict__ P2,
                                            unsigned short* __restrict__ c2b,
                                            float* __restrict__ d2) {
    __shared__ float cs[16 * 108];
    __shared__ float aggs[16 * 108];
    __shared__ float h1s[16 * 17];
    __shared__ float ws2[16 * 17];
    __shared__ float p2s[8 * 17];
    __shared__ float bvs[16];
    __shared__ int idxs[256];
    int tid = threadIdx.x;
    for (int i = tid; i < 1728; i += 256) cs[i] = C1ext[i];
    {
        int f = tid >> 4, k = tid & 15;
        ws2[f * 17 + k] = w2_pre[f * 32 + 16 + k];
    }
    if (tid < 128) p2s[(tid >> 4) * 17 + (tid & 15)] = P2[tid];
    if (tid < 16) bvs[tid] = bvp1[tid];
    idxs[tid] = src[blockIdx.x * 256 + tid];
    __syncthreads();

    int g = tid >> 4;           // node-in-block
    int L = tid & 15;           // lane-in-node: feats 2L, 2L+1
    {
        int id[K_DEG];
#pragma unroll
        for (int e = 0; e < K_DEG; ++e) id[e] = idxs[g * 16 + e];
        unsigned int v[K_DEG];
#pragma unroll
        for (int e = 0; e < K_DEG; ++e) v[e] = c1u[id[e] * 16 + L];
        float s0 = 0.f, q0 = 0.f, n0 = 1e30f, x0 = -1e30f;
        float s1 = 0.f, q1 = 0.f, n1 = 1e30f, x1 = -1e30f;
#pragma unroll
        for (int e = 0; e < K_DEG; ++e) {
            float a = bf2f((unsigned short)(v[e] & 0xffff));
            float b = bf2f((unsigned short)(v[e] >> 16));
            s0 += a; q0 += a * a; n0 = fminf(n0, a); x0 = fmaxf(x0, a);
            s1 += b; q1 += b * b; n1 = fminf(n1, b); x1 = fmaxf(x1, b);
        }
        float me0 = s0 * (1.f / 16.f), me1 = s1 * (1.f / 16.f);
        float sd0 = sqrtf(fmaxf(q0 * (1.f / 16.f) - me0 * me0, 0.f) + EPSV);
        float sd1 = sqrtf(fmaxf(q1 * (1.f / 16.f) - me1 * me1, 0.f) + EPSV);
        if (L < 13) {
            float* r = aggs + g * 108 + 2 * L;
            *(float2*)(r)      = make_float2(me0, me1);
            *(float2*)(r + 26) = make_float2(n0, n1);
            *(float2*)(r + 52) = make_float2(x0, x1);
            *(float2*)(r + 78) = make_float2(sd0, sd1);
        } else if (L == 13) {
            *(float4*)(aggs + g * 108 + 104) = make_float4(0.f, 0.f, 0.f, 0.f);
        }
    }
    __syncthreads();

    {   // h1 = relu(C1ext @ agg + d1 + bvp1)
        int nl = tid >> 4, o = tid & 15;
        int nn = blockIdx.x * 16 + nl;
        float s = bvs[o] + d1[nn * 16 + o];
        const float4* c4 = (const float4*)(cs + o * 108);
        const float4* a4 = (const float4*)(aggs + nl * 108);
#pragma unroll
        for (int j = 0; j < 27; ++j) {
            float4 cv = c4[j], av = a4[j];
            s += cv.x * av.x + cv.y * av.y + cv.z * av.z + cv.w * av.w;
        }
        h1s[nl * 17 + o] = fmaxf(s, 0.f);
    }
    __syncthreads();

    {   // c2 = Ws2 @ h1 (bf16)
        int nl = tid >> 4, f = tid & 15;
        int nn = blockIdx.x * 16 + nl;
        const float* hr = h1s + nl * 17;
        float s = 0.f;
#pragma unroll
        for (int k = 0; k < 16; ++k) s += ws2[f * 17 + k] * hr[k];
        c2b[nn * 16 + f] = f2bf(s);
    }
    if (tid < 128) {   // d2 = P2 @ h1
        int nl = tid >> 3, o = tid & 7;
        int nn = blockIdx.x * 16 + nl;
        const float* hr = h1s + nl * 17;
        float s = 0.f;
#pragma unroll
        for (int k = 0; k < 16; ++k) s += p2s[o * 17 + k] * hr[k];
        d2[nn * 8 + o] = s;
    }
}

// ---------------------------------------------------------------------------
// agg2: 8 lanes/node, 32 nodes/block.  uint gathers, LDS-staged indices.
// ---------------------------------------------------------------------------
__global__ void __launch_bounds__(256) agg2(const unsigned int* __restrict__ c2u,
                                            const int* __restrict__ src,
                                            const float* __restrict__ d2,
                                            const float* __restrict__ C2p,
                                            const float* __restrict__ bvp2,
                                            float* __restrict__ h2) {
    __shared__ float cs[8 * 68];
    __shared__ float ag[32 * 68];
    __shared__ float bvs[8];
    __shared__ int idxs[512];
    int tid = threadIdx.x;
    for (int i = tid; i < 544; i += 256) cs[i] = C2p[i];
    if (tid < 8) bvs[tid] = bvp2[tid];
    idxs[tid] = src[blockIdx.x * 512 + tid];
    idxs[tid + 256] = src[blockIdx.x * 512 + 256 + tid];
    __syncthreads();

    int g = tid >> 3;           // 0..31
    int L = tid & 7;            // feats 2L, 2L+1
    {
        int id[K_DEG];
#pragma unroll
        for (int e = 0; e < K_DEG; ++e) id[e] = idxs[g * 16 + e];
        unsigned int v[K_DEG];
#pragma unroll
        for (int e = 0; e < K_DEG; ++e) v[e] = c2u[id[e] * 8 + L];
        float s0 = 0.f, q0 = 0.f, n0 = 1e30f, x0 = -1e30f;
        float s1 = 0.f, q1 = 0.f, n1 = 1e30f, x1 = -1e30f;
#pragma unroll
        for (int e = 0; e < K_DEG; ++e) {
            float a = bf2f((unsigned short)(v[e] & 0xffff));
            float b = bf2f((unsigned short)(v[e] >> 16));
            s0 += a; q0 += a * a; n0 = fminf(n0, a); x0 = fmaxf(x0, a);
            s1 += b; q1 += b * b; n1 = fminf(n1, b); x1 = fmaxf(x1, b);
        }
        float me0 = s0 * (1.f / 16.f), me1 = s1 * (1.f / 16.f);
        float sd0 = sqrtf(fmaxf(q0 * (1.f / 16.f) - me0 * me0, 0.f) + EPSV);
        float sd1 = sqrtf(fmaxf(q1 * (1.f / 16.f) - me1 * me1, 0.f) + EPSV);
        float* r = ag + g * 68 + 2 * L;
        *(float2*)(r)      = make_float2(me0, me1);
        *(float2*)(r + 16) = make_float2(n0, n1);
        *(float2*)(r + 32) = make_float2(x0, x1);
        *(float2*)(r + 48) = make_float2(sd0, sd1);
        if (L == 0) *(float4*)(ag + g * 68 + 64) = make_float4(0.f, 0.f, 0.f, 0.f);
    }
    __syncthreads();

    {
        int nl = tid >> 3, o = tid & 7;
        int nn = blockIdx.x * 32 + nl;
        float s = bvs[o] + d2[nn * 8 + o];
        const float4* c4 = (const float4*)(cs + o * 68);
        const float4* a4 = (const float4*)(ag + nl * 68);
#pragma unroll
        for (int j = 0; j < 17; ++j) {
            float4 cv = c4[j], av = a4[j];
            s += cv.x * av.x + cv.y * av.y + cv.z * av.z + cv.w * av.w;
        }
        h2[nn * 8 + o] = fmaxf(s, 0.f);
    }
}

// ---------------------------------------------------------------------------
// pool (50 contiguous nodes / graph) + fc + log_softmax.  1 wave per graph.
// ---------------------------------------------------------------------------
__global__ void pool_fc(const float* __restrict__ h2, const float* __restrict__ fc_w,
                        const float* __restrict__ fc_b, float* __restrict__ out) {
    int wave = threadIdx.x >> 6;
    int lane = threadIdx.x & 63;
    int g = blockIdx.x * 4 + wave;
    float s0 = 0.f, s1 = 0.f;
    if (lane < 50) {
        const float* hr = h2 + (g * 50 + lane) * 8;
        float v[8];
#pragma unroll
        for (int o = 0; o < 8; ++o) v[o] = hr[o];
#pragma unroll
        for (int o = 0; o < 8; ++o) { s0 += fc_w[o] * v[o]; s1 += fc_w[8 + o] * v[o]; }
    }
#pragma unroll
    for (int off = 32; off > 0; off >>= 1) {
        s0 += __shfl_down(s0, off);
        s1 += __shfl_down(s1, off);
    }
    if (lane == 0) {
        float l0 = s0 + fc_b[0], l1 = s1 + fc_b[1];
        float m = fmaxf(l0, l1);
        float lse = m + logf(expf(l0 - m) + expf(l1 - m));
        out[g * 2]     = l0 - lse;
        out[g * 2 + 1] = l1 - lse;
    }
}

extern "C" void kernel_launch(void* const* d_in, const int* in_sizes, int n_in,
                              void* d_out, int out_size, void* d_ws, size_t ws_size,
                              hipStream_t stream) {
    const float* x       = (const float*)d_in[0];
    const int*   eidx    = (const int*)d_in[1];   // [2][E]; row 0 = src
    const float* w1_pre  = (const float*)d_in[3];
    const float* b1_pre  = (const float*)d_in[4];
    const float* w1_post = (const float*)d_in[5];
    const float* b1_post = (const float*)d_in[6];
    const float* w1_lin  = (const float*)d_in[7];
    const float* b1_lin  = (const float*)d_in[8];
    const float* w2_pre  = (const float*)d_in[9];
    const float* b2_pre  = (const float*)d_in[10];
    const float* w2_post = (const float*)d_in[11];
    const float* b2_post = (const float*)d_in[12];
    const float* w2_lin  = (const float*)d_in[13];
    const float* b2_lin  = (const float*)d_in[14];
    const float* fc_w    = (const float*)d_in[15];
    const float* fc_b    = (const float*)d_in[16];
    float* out = (float*)d_out;
    const int* src = eidx;

    char* ws = (char*)d_ws;
    unsigned int*   c1u = (unsigned int*)ws;                  // N*16*4  = 12.8 MB
    unsigned short* c2b = (unsigned short*)(ws + 12800000);   // N*16*2  =  6.4 MB
    float* d1  = (float*)(ws + 19200000);                     // N*16*4  = 12.8 MB
    float* d2  = (float*)(ws + 32000000);                     // N*8*4   =  6.4 MB
    float* h2  = (float*)(ws + 38400000);                     // N*8*4   =  6.4 MB
    float* C1ext = (float*)(ws + 44800000);                   // 1728
    float* bvp1  = C1ext + 1728;                              // 16
    float* P1    = bvp1 + 16;                                 // 400
    float* C2p   = P1 + 400;                                  // 544
    float* bvp2  = C2p + 544;                                 // 8
    float* P2    = bvp2 + 8;                                  // 128

    prep<<<2, 256, 0, stream>>>(w1_pre, b1_pre, w1_post, b1_post, w1_lin, b1_lin,
                                w2_pre, b2_pre, w2_post, b2_post, w2_lin, b2_lin,
                                C1ext, bvp1, P1, C2p, bvp2, P2);
    pre1<<<(N_NODES + 255) / 256, 256, 0, stream>>>(x, w1_pre, P1, c1u, d1);
    agg1<<<N_NODES / 16, 256, 0, stream>>>(c1u, src, d1, C1ext, bvp1, w2_pre, P2, c2b, d2);
    agg2<<<N_NODES / 32, 256, 0, stream>>>((const unsigned int*)c2b, src, d2, C2p, bvp2, h2);
    pool_fc<<<G_GRAPHS / 4, 256, 0, stream>>>(h2, fc_w, fc_b, out);
}